// Round 10
// baseline (77.168 us; speedup 1.0000x reference)
//
#include <hip/hip_runtime.h>

// QuantumLayer: 4-qubit, 4-layer VQC over batch B.
// R16 = R14 (named v2f, 2 elems/thread, best @74.5-74.8us) with layers 1..3
// ROLLED into a real 3-iteration loop (#pragma unroll 1).
//  Theory: the ~2200-inst (~18KB) straight-line body is instruction-fetch
//  bound — zero I-cache reuse per wave. Evidence: perf tracks code footprint
//  (scalar 2x insts -> 1.5x slower; 2-stream 2x body -> slower) while
//  occupancy (R7), ILP (R13), and LDS latency (R15) are all null. Rolling
//  shrinks the hot body to ~600 insts (~5KB, I$-resident, reused 3x).
//  Enabler: layer-3's RZ=I lives in the LDS DATA (az=0 -> ai=bi=0), so the
//  generic gate build is exact for all 3 iterations -> identical loop code.
//  Cost: loop-carried CNOT permutation -> ~32 v_mov_b64/iter (~3% issue).
//  Kept: fused precompute, L0 product build, folded butterfly measurement.
// State indexing: flat k = w0*8 + w1*4 + w2*2 + w3  (wire i -> bit (3-i)).

typedef float v2f __attribute__((ext_vector_type(2)));

// G = M * RX(c,s) is SU(2): G = [[g, d], [-conj(d), conj(g)]].
// Mp = per-layer LDS base (16 splatted v2f quads); Q = wire.
#define MAKE_G2(Mp, Q) do {                                       \
    v2f m_ar = (Mp)[(Q) * 4 + 0], m_ai = (Mp)[(Q) * 4 + 1];       \
    v2f m_br = (Mp)[(Q) * 4 + 2], m_bi = (Mp)[(Q) * 4 + 3];       \
    gr = m_ar * cx##Q + m_bi * sx##Q;                             \
    gi = m_ai * cx##Q - m_br * sx##Q;                             \
    dr = m_ai * sx##Q + m_br * cx##Q;                             \
    di = m_bi * cx##Q - m_ar * sx##Q;                             \
  } while (0)

// ---- gate application on a named pair ----
#define GATE_APPLY(K0, K1) do {                                   \
    v2f a0r = sr_##K0, a0i = si_##K0;                             \
    v2f a1r = sr_##K1, a1i = si_##K1;                             \
    sr_##K0 = gr * a0r - gi * a0i + dr * a1r - di * a1i;          \
    si_##K0 = gr * a0i + gi * a0r + dr * a1i + di * a1r;          \
    sr_##K1 = gr * a1r + gi * a1i - dr * a0r - di * a0i;          \
    si_##K1 = gr * a1i - gi * a1r - dr * a0i + di * a0r;          \
  } while (0)

#define SU2_W0 do { GATE_APPLY(0,8);  GATE_APPLY(1,9);   GATE_APPLY(2,10);  GATE_APPLY(3,11); \
                    GATE_APPLY(4,12); GATE_APPLY(5,13);  GATE_APPLY(6,14);  GATE_APPLY(7,15); } while (0)
#define SU2_W1 do { GATE_APPLY(0,4);  GATE_APPLY(1,5);   GATE_APPLY(2,6);   GATE_APPLY(3,7);  \
                    GATE_APPLY(8,12); GATE_APPLY(9,13);  GATE_APPLY(10,14); GATE_APPLY(11,15); } while (0)
#define SU2_W2 do { GATE_APPLY(0,2);  GATE_APPLY(1,3);   GATE_APPLY(4,6);   GATE_APPLY(5,7);  \
                    GATE_APPLY(8,10); GATE_APPLY(9,11);  GATE_APPLY(12,14); GATE_APPLY(13,15); } while (0)
#define SU2_W3 do { GATE_APPLY(0,1);  GATE_APPLY(2,3);   GATE_APPLY(4,5);   GATE_APPLY(6,7);  \
                    GATE_APPLY(8,9);  GATE_APPLY(10,11); GATE_APPLY(12,13); GATE_APPLY(14,15); } while (0)

// CNOT block (2,3)(1,2)(0,1)(3,0): SSA renames (loop-carried -> movs).
#define SWAPK(A, B) do { v2f t_r = sr_##A; sr_##A = sr_##B; sr_##B = t_r; \
                         v2f t_i = si_##A; si_##A = si_##B; si_##B = t_i; } while (0)
#define CNOTS do { SWAPK(2,3);  SWAPK(6,7);  SWAPK(10,11); SWAPK(14,15); \
                   SWAPK(4,6);  SWAPK(5,7);  SWAPK(12,14); SWAPK(13,15); \
                   SWAPK(8,12); SWAPK(9,13); SWAPK(10,14); SWAPK(11,15); \
                   SWAPK(1,9);  SWAPK(3,11); SWAPK(5,13);  SWAPK(7,15); } while (0)

// Layer-0 product-state expansion: K keeps new-bit=0 (* g), KP gets
// new-bit=1 (* -conj(d) = (-dr, +di)).
#define L0_EXPAND(K, KP) do {                   \
    v2f e_ar = sr_##K, e_ai = si_##K;           \
    sr_##KP = -(dr * e_ar) - di * e_ai;         \
    si_##KP = di * e_ar - dr * e_ai;            \
    sr_##K  = gr * e_ar - gi * e_ai;            \
    si_##K  = gr * e_ai + gi * e_ar;            \
  } while (0)

#define PSQ(K) (sr_##K * sr_##K + si_##K * si_##K)

__global__ __launch_bounds__(256) void qlayer_main(const float* __restrict__ x,
                                                   const float* __restrict__ w,
                                                   float* __restrict__ out) {
  // ---- Fused precompute: M = RZ(pz)*RY(py) per (layer, wire); layer 3 uses
  // az=0 (RZ=I, exact) so its LDS quads have ai=bi=0 and the GENERIC gate
  // build is correct for every layer. Splatted v2f quads in LDS (512 B). ----
  __shared__ v2f Msh[16 * 4];
  int tid = threadIdx.x;
  if (tid < 16) {
    int l = tid >> 2, q = tid & 3;
    float ay = 0.5f * w[8 * l + q];
    float az = (l == 3) ? 0.0f : 0.5f * w[8 * l + 4 + q];
    float cy = __cosf(ay), sy = __sinf(ay);
    float cz = __cosf(az), sz = __sinf(az);
    float ar = cz * cy, ai = -sz * cy, br = -cz * sy, bi = sz * sy;
    Msh[tid * 4 + 0] = v2f{ar, ar};
    Msh[tid * 4 + 1] = v2f{ai, ai};
    Msh[tid * 4 + 2] = v2f{br, br};
    Msh[tid * 4 + 3] = v2f{bi, bi};
  }

  int t = blockIdx.x * blockDim.x + tid;  // owns batch elems 2t, 2t+1
  const float4* x4 = reinterpret_cast<const float4*>(x);
  float4 xv0 = x4[2 * t + 0], xv1 = x4[2 * t + 1];

  v2f cx0 = v2f{__cosf(0.5f * xv0.x), __cosf(0.5f * xv1.x)};
  v2f sx0 = v2f{__sinf(0.5f * xv0.x), __sinf(0.5f * xv1.x)};
  v2f cx1 = v2f{__cosf(0.5f * xv0.y), __cosf(0.5f * xv1.y)};
  v2f sx1 = v2f{__sinf(0.5f * xv0.y), __sinf(0.5f * xv1.y)};
  v2f cx2 = v2f{__cosf(0.5f * xv0.z), __cosf(0.5f * xv1.z)};
  v2f sx2 = v2f{__sinf(0.5f * xv0.z), __sinf(0.5f * xv1.z)};
  v2f cx3 = v2f{__cosf(0.5f * xv0.w), __cosf(0.5f * xv1.w)};
  v2f sx3 = v2f{__sinf(0.5f * xv0.w), __sinf(0.5f * xv1.w)};

  __syncthreads();  // Msh ready

  // ---- State: named v2f (SSA-direct; aggregate demotion impossible) ----
  v2f sr_0, sr_1, sr_2, sr_3, sr_4, sr_5, sr_6, sr_7;
  v2f sr_8, sr_9, sr_10, sr_11, sr_12, sr_13, sr_14, sr_15;
  v2f si_0, si_1, si_2, si_3, si_4, si_5, si_6, si_7;
  v2f si_8, si_9, si_10, si_11, si_12, si_13, si_14, si_15;
  v2f gr, gi, dr, di;

  // ---- Layer 0 on |0000>: product state built in-place LSB-first ----
  MAKE_G2(Msh, 3);
  sr_0 = gr;  si_0 = gi;  sr_1 = -dr; si_1 = di;
  MAKE_G2(Msh, 2);
  L0_EXPAND(1, 3); L0_EXPAND(0, 2);
  MAKE_G2(Msh, 1);
  L0_EXPAND(3, 7); L0_EXPAND(2, 6); L0_EXPAND(1, 5); L0_EXPAND(0, 4);
  MAKE_G2(Msh, 0);
  L0_EXPAND(7, 15); L0_EXPAND(6, 14); L0_EXPAND(5, 13); L0_EXPAND(4, 12);
  L0_EXPAND(3, 11); L0_EXPAND(2, 10); L0_EXPAND(1, 9);  L0_EXPAND(0, 8);
  CNOTS;

  // ---- Layers 1..3: ROLLED (identical code each iteration; layer-3 RZ=I
  // is baked into the LDS data). Hot body ~5KB, I$-resident, reused 3x. ----
#pragma unroll 1
  for (int l = 1; l < 4; ++l) {
    const v2f* Ml = &Msh[l * 16];
    MAKE_G2(Ml, 0); SU2_W0;
    MAKE_G2(Ml, 1); SU2_W1;
    MAKE_G2(Ml, 2); SU2_W2;
    MAKE_G2(Ml, 3); SU2_W3;
    CNOTS;
  }

  // ---- Measurement: butterfly over p_k = |amp_k|^2;
  // o_j = sum_k p_k * (bit(3-j)? -1 : +1). ----
  v2f p0 = PSQ(0),  p1 = PSQ(1),  p2 = PSQ(2),  p3 = PSQ(3);
  v2f p4 = PSQ(4),  p5 = PSQ(5),  p6 = PSQ(6),  p7 = PSQ(7);
  v2f p8 = PSQ(8),  p9 = PSQ(9),  pa = PSQ(10), pb = PSQ(11);
  v2f pc = PSQ(12), pd = PSQ(13), pe = PSQ(14), pf = PSQ(15);

  v2f s20 = p0 + p1, d20 = p0 - p1,  s21 = p2 + p3, d21 = p2 - p3;
  v2f s22 = p4 + p5, d22 = p4 - p5,  s23 = p6 + p7, d23 = p6 - p7;
  v2f s24 = p8 + p9, d24 = p8 - p9,  s25 = pa + pb, d25 = pa - pb;
  v2f s26 = pc + pd, d26 = pc - pd,  s27 = pe + pf, d27 = pe - pf;
  v2f o3 = ((d20 + d21) + (d22 + d23)) + ((d24 + d25) + (d26 + d27));

  v2f s40 = s20 + s21, d40 = s20 - s21, s41 = s22 + s23, d41 = s22 - s23;
  v2f s42 = s24 + s25, d42 = s24 - s25, s43 = s26 + s27, d43 = s26 - s27;
  v2f o2 = (d40 + d41) + (d42 + d43);

  v2f s8a = s40 + s41, s8b = s42 + s43;
  v2f d8a = s40 - s41, d8b = s42 - s43;
  v2f o1 = d8a + d8b;
  v2f o0 = s8a - s8b;

  float4* o4 = reinterpret_cast<float4*>(out);
  o4[2 * t + 0] = make_float4(o0.x, o1.x, o2.x, o3.x);
  o4[2 * t + 1] = make_float4(o0.y, o1.y, o2.y, o3.y);
}

extern "C" void kernel_launch(void* const* d_in, const int* in_sizes, int n_in,
                              void* d_out, int out_size, void* d_ws, size_t ws_size,
                              hipStream_t stream) {
  const float* x = (const float*)d_in[0];
  const float* w = (const float*)d_in[1];
  float* out = (float*)d_out;
  int nb = in_sizes[0] / 4;   // batch elements; B=524288
  int threads = nb / 2;       // 2 elements per thread -> 262144
  int blocks = threads / 256; // exact: 1024 blocks
  hipLaunchKernelGGL(qlayer_main, dim3(blocks), dim3(256), 0, stream, x, w, out);
}